// Round 7
// baseline (503.194 us; speedup 1.0000x reference)
//
#include <hip/hip_runtime.h>
#include <hip/hip_bf16.h>

#define T_LEN 96
#define C_CH  66
#define FIN   7128   // 9*66*12
#define KPAD  7168   // 224*32
#define NFC1  1936
#define NPAD  2048
#define NCLS  14

typedef __bf16 bf16x8 __attribute__((ext_vector_type(8)));
typedef float  f32x4  __attribute__((ext_vector_type(4)));

#define GLD_LDS(gp, lp) __builtin_amdgcn_global_load_lds(                     \
    (__attribute__((address_space(1))) void*)(gp),                            \
    (__attribute__((address_space(3))) void*)(lp), 16, 0, 0)

// ---------------------------------------------------------------------------
// Kernel 0: transpose x (B, T*C) -> xT (T*C, B) so conv lanes (lane=b) read
// coalesced. 64x64 LDS tile, +1 pad.
__global__ __launch_bounds__(256) void transpose_kernel(
    const float* __restrict__ x, float* __restrict__ xT, int B)
{
    __shared__ float tile[64][65];
    const int t = threadIdx.x & 63;
    const int w = threadIdx.x >> 6;
    const int tc0 = blockIdx.x * 64;     // 6336 / 64 = 99
    const int b0  = blockIdx.y * 64;     // B / 64
    #pragma unroll
    for (int j = 0; j < 16; j++) {
        const int r = w * 16 + j;
        tile[r][t] = x[(size_t)(b0 + r) * (T_LEN * C_CH) + tc0 + t];
    }
    __syncthreads();
    #pragma unroll
    for (int j = 0; j < 16; j++) {
        const int r = w * 16 + j;
        xT[(size_t)(tc0 + r) * B + b0 + t] = tile[t][r];
    }
}

// ---------------------------------------------------------------------------
// Kernel 1: w_fc1 (1936 x 7128 fp32) -> bf16 (2048 x 7168), zero padded.
__global__ __launch_bounds__(256) void pad_w_kernel(
    const float* __restrict__ w, __hip_bfloat16* __restrict__ wb)
{
    int idx = blockIdx.x * 256 + threadIdx.x;     // chunk id, total 2048*896
    int row = idx / 896;
    int cc  = idx - row * 896;                    // 896 chunks of 8 per row
    float4 a = {0.f, 0.f, 0.f, 0.f}, b = {0.f, 0.f, 0.f, 0.f};
    if (row < NFC1 && cc < 891) {                 // 891*8 = 7128
        const float4* src = (const float4*)(w + (size_t)row * FIN + cc * 8);
        a = src[0];
        b = src[1];
    }
    __align__(16) __hip_bfloat16 v[8];
    v[0] = __float2bfloat16(a.x); v[1] = __float2bfloat16(a.y);
    v[2] = __float2bfloat16(a.z); v[3] = __float2bfloat16(a.w);
    v[4] = __float2bfloat16(b.x); v[5] = __float2bfloat16(b.y);
    v[6] = __float2bfloat16(b.z); v[7] = __float2bfloat16(b.w);
    *(int4*)(wb + (size_t)row * KPAD + cc * 8) = *(const int4*)v;
}

// ---------------------------------------------------------------------------
// Kernel 2: conv branch, per-lane pipeline with live set <= ~115 regs BY
// CONSTRUCTION (allocator targets 128 for wave64 — fit under it, never
// fight it). 8 tiles of 6 stage-2 positions; stage-3 finalized
// INCREMENTALLY from a sliding window s2w[4][K+2] of stage-2-pooled values
// (window index = r+k, derived: i = g - (3tt-(W-3)) = r+k). One virtual
// epilogue tile (tt==8) flushes the last PAD outputs. pend[] carries the
// even pooling half across tiles. One lane = one (b,c); grid (B/64, C).
template <int K, bool DO_EXTRA>
__global__ __launch_bounds__(64, 3) void conv_kernel(
    const float* __restrict__ x, int ts, int bs, int cs,
    const float* __restrict__ wS, const float* __restrict__ bS,
    const float* __restrict__ wI1, const float* __restrict__ bI1,
    const float* __restrict__ wI2, const float* __restrict__ bI2,
    __hip_bfloat16* __restrict__ feat, int out_off)
{
    constexpr int PAD = K / 2;
    constexpr int XW  = 12 + 6 * PAD;   // x window per tile
    constexpr int THW = 6 + 2 * PAD;    // stage-1 pooled window per tile
    constexpr int W   = 3 + 2 * PAD;    // stage-2 pooled sliding window

    const int lane = threadIdx.x;
    const int b = blockIdx.x * 64 + lane;
    const int c = blockIdx.y;
    const float* xb = x + (size_t)b * bs + (size_t)c * cs;
    __hip_bfloat16* frow = feat + (size_t)b * KPAD + c * 108;

    const float* wi1 = wI1 + c * (4 * 8 * K);
    const float* bi1 = bI1 + c * 4;
    const float* wi2 = wI2 + c * (4 * 4 * K);
    const float* bi2 = bI2 + c * 4;

    if (DO_EXTRA) {
        // orig = pool2^3 = mean of 8 consecutive (loads are L1/L2-hot reuse)
        #pragma unroll
        for (int q = 0; q < 12; q++) {
            float s = 0.f;
            #pragma unroll
            for (int k = 0; k < 8; k++) s += xb[(size_t)(q * 8 + k) * ts];
            frow[q] = __float2bfloat16(s * 0.125f);
        }
        if (c == 0) {                   // zero K-pad tail once per row
            int4* tail = (int4*)(feat + (size_t)b * KPAD + FIN);
            const int4 z = {0, 0, 0, 0};
            #pragma unroll
            for (int i = 0; i < 5; i++) tail[i] = z;
        }
    }

    float s2w[4][W];                    // stage-2 pooled window (per stage-3 ic)
    float pend[4] = {0.f, 0.f, 0.f, 0.f};

    #pragma unroll
    for (int tt = 0; tt <= 8; tt++) {   // tt==8: epilogue flush
        if (tt < 8) {
            // x window: global t = 12tt - 3PAD + i, zero outside [0,96)
            float xw[XW];
            #pragma unroll
            for (int i = 0; i < XW; i++) {
                const int t = 12 * tt - 3 * PAD + i;     // compile-time
                xw[i] = (t >= 0 && t < T_LEN) ? xb[(size_t)t * ts] : 0.f;
            }

            float s2a[4][6];
            #pragma unroll
            for (int oc = 0; oc < 4; oc++) {
                const float bv = bi1[oc];
                #pragma unroll
                for (int q = 0; q < 6; q++) s2a[oc][q] = bv;
            }

            #pragma unroll 1
            for (int ic = 0; ic < 8; ic++) {
                const float bs1 = bS[ic];
                float thw[THW];         // stage-1 pooled window (this ic)
                #pragma unroll
                for (int j = 0; j < THW; j++) {
                    const int jg = 6 * tt - PAD + j;     // compile-time
                    if (jg < 0 || jg >= 48) { thw[j] = 0.f; continue; }
                    float y0 = bs1, y1 = bs1;
                    #pragma unroll
                    for (int k = 0; k < K; k++) {
                        const float w = wS[ic * K + k];
                        y0 = fmaf(w, xw[2 * j + k], y0);
                        y1 = fmaf(w, xw[2 * j + 1 + k], y1);
                    }
                    thw[j] = 0.5f * (fmaxf(y0, 0.f) + fmaxf(y1, 0.f));
                }
                #pragma unroll
                for (int q = 0; q < 6; q++) {
                    #pragma unroll
                    for (int oc = 0; oc < 4; oc++) {
                        float a = s2a[oc][q];
                        #pragma unroll
                        for (int k = 0; k < K; k++)
                            a = fmaf(wi1[(oc * 8 + ic) * K + k], thw[q + k], a);
                        s2a[oc][q] = a;
                    }
                }
            }

            // slide window by 3, insert 3 new stage-2 pooled values
            #pragma unroll
            for (int ch = 0; ch < 4; ch++) {
                #pragma unroll
                for (int i = 0; i < W - 3; i++)
                    s2w[ch][i] = (tt == 0) ? 0.f : s2w[ch][i + 3];
                #pragma unroll
                for (int r = 0; r < 3; r++)
                    s2w[ch][W - 3 + r] =
                        0.5f * (fmaxf(s2a[ch][2 * r], 0.f) +
                                fmaxf(s2a[ch][2 * r + 1], 0.f));
            }
        } else {
            // epilogue: slide in zeros
            #pragma unroll
            for (int ch = 0; ch < 4; ch++) {
                #pragma unroll
                for (int i = 0; i < W - 3; i++) s2w[ch][i] = s2w[ch][i + 3];
                #pragma unroll
                for (int r = 0; r < 3; r++) s2w[ch][W - 3 + r] = 0.f;
            }
        }

        // stage-3: finalize pre-pool outputs po = 3tt - PAD + r (all taps
        // now in window; window index = r + k; OOB taps statically dropped)
        #pragma unroll
        for (int r = 0; r < 3; r++) {
            const int po = 3 * tt - PAD + r;             // compile-time
            if (po < 0 || po >= 24) continue;
            float y[4];
            #pragma unroll
            for (int oc = 0; oc < 4; oc++) y[oc] = bi2[oc];
            #pragma unroll
            for (int ch = 0; ch < 4; ch++) {
                #pragma unroll
                for (int k = 0; k < K; k++) {
                    const int g = po - PAD + k;          // compile-time
                    if (g < 0 || g >= 24) continue;
                    const float v = s2w[ch][r + k];
                    #pragma unroll
                    for (int oc = 0; oc < 4; oc++)
                        y[oc] = fmaf(wi2[(oc * 4 + ch) * K + k], v, y[oc]);
                }
            }
            if ((po & 1) == 0) {
                #pragma unroll
                for (int oc = 0; oc < 4; oc++) pend[oc] = fmaxf(y[oc], 0.f);
            } else {
                #pragma unroll
                for (int oc = 0; oc < 4; oc++)
                    frow[out_off + oc * 12 + (po >> 1)] = __float2bfloat16(
                        0.5f * (pend[oc] + fmaxf(y[oc], 0.f)));
            }
        }
    }
}

// ---------------------------------------------------------------------------
// Kernel 3: FC1 GEMM, A(2048xKPAD bf16) * W(2048xKPAD bf16)^T, split-K,
// plain fp32 stores into slabs (no atomics); bias/relu/reduce in fc2.
__global__ __launch_bounds__(256) void gemm_kernel(
    const __hip_bfloat16* __restrict__ A,
    const __hip_bfloat16* __restrict__ Bw,
    float* __restrict__ Cm, int kchunk)
{
    __shared__ __align__(16) __hip_bfloat16 As[4096];  // 128 x 32
    __shared__ __align__(16) __hip_bfloat16 Bs[4096];  // 128 x 32

    const int tid  = threadIdx.x;
    const int lane = tid & 63;
    const int wid  = tid >> 6;
    const int m0 = blockIdx.y * 128;
    const int n0 = blockIdx.x * 128;
    const int wm = (wid >> 1) * 64;
    const int wn = (wid & 1) * 64;
    const int lr = lane & 15;
    const int quad = lane >> 4;

    const int r0 = tid >> 2, c0 = (tid & 3) * 8;
    const __hip_bfloat16* gA0 = A  + (size_t)(m0 + r0) * KPAD + c0;
    const __hip_bfloat16* gA1 = gA0 + (size_t)64 * KPAD;
    const __hip_bfloat16* gB0 = Bw + (size_t)(n0 + r0) * KPAD + c0;
    const __hip_bfloat16* gB1 = gB0 + (size_t)64 * KPAD;
    __hip_bfloat16* lA0 = As + wid * 512;
    __hip_bfloat16* lA1 = As + 2048 + wid * 512;
    __hip_bfloat16* lB0 = Bs + wid * 512;
    __hip_bfloat16* lB1 = Bs + 2048 + wid * 512;

    f32x4 acc[4][4] = {};

    const int kBeg = blockIdx.z * kchunk;
    const int kEnd = kBeg + kchunk;
    for (int k0 = kBeg; k0 < kEnd; k0 += 32) {
        __syncthreads();
        GLD_LDS(gA0 + k0, lA0);
        GLD_LDS(gA1 + k0, lA1);
        GLD_LDS(gB0 + k0, lB0);
        GLD_LDS(gB1 + k0, lB1);
        __syncthreads();
        bf16x8 af[4], bfr[4];
        #pragma unroll
        for (int mt = 0; mt < 4; mt++)
            af[mt] = *(const bf16x8*)(As + (wm + mt * 16 + lr) * 32 + quad * 8);
        #pragma unroll
        for (int nt = 0; nt < 4; nt++)
            bfr[nt] = *(const bf16x8*)(Bs + (wn + nt * 16 + lr) * 32 + quad * 8);
        #pragma unroll
        for (int mt = 0; mt < 4; mt++)
            #pragma unroll
            for (int nt = 0; nt < 4; nt++)
                acc[mt][nt] = __builtin_amdgcn_mfma_f32_16x16x32_bf16(
                    af[mt], bfr[nt], acc[mt][nt], 0, 0, 0);
    }

    // epilogue: C/D layout col = lane&15, row = quad*4 + reg
    float* Cs = Cm + (size_t)blockIdx.z * NPAD * NPAD;
    #pragma unroll
    for (int mt = 0; mt < 4; mt++) {
        #pragma unroll
        for (int nt = 0; nt < 4; nt++) {
            const int col = n0 + wn + nt * 16 + lr;
            const int rb  = m0 + wm + mt * 16 + quad * 4;
            #pragma unroll
            for (int r = 0; r < 4; r++)
                Cs[(size_t)(rb + r) * NPAD + col] = acc[mt][nt][r];
        }
    }
}

// ---------------------------------------------------------------------------
// Kernel 4: reduce split-K slabs + bias + relu, then FC2. One block per row.
__global__ __launch_bounds__(256) void fc2_kernel(
    const float* __restrict__ h1, const float* __restrict__ b1,
    const float* __restrict__ w2, const float* __restrict__ b2,
    float* __restrict__ out, int nslab)
{
    const int b = blockIdx.x;
    const int tid = threadIdx.x;
    float acc[NCLS];
    #pragma unroll
    for (int o = 0; o < NCLS; o++) acc[o] = 0.f;
    for (int n = tid; n < NFC1; n += 256) {
        float hv = b1[n];
        for (int s = 0; s < nslab; s++)
            hv += h1[(size_t)s * NPAD * NPAD + (size_t)b * NPAD + n];
        float h = fmaxf(hv, 0.f);
        #pragma unroll
        for (int o = 0; o < NCLS; o++)
            acc[o] = fmaf(h, w2[o * NFC1 + n], acc[o]);
    }
    __shared__ float red[4][NCLS];
    #pragma unroll
    for (int o = 0; o < NCLS; o++) {
        float v = acc[o];
        #pragma unroll
        for (int s = 32; s > 0; s >>= 1) v += __shfl_down(v, s);
        if ((tid & 63) == 0) red[tid >> 6][o] = v;
    }
    __syncthreads();
    if (tid < NCLS)
        out[b * NCLS + tid] = red[0][tid] + red[1][tid] + red[2][tid] +
                              red[3][tid] + b2[tid];
}

// ---------------------------------------------------------------------------
extern "C" void kernel_launch(void* const* d_in, const int* in_sizes, int n_in,
                              void* d_out, int out_size, void* d_ws, size_t ws_size,
                              hipStream_t stream)
{
    (void)n_in; (void)out_size;
    const float* x     = (const float*)d_in[0];
    const float* w_hs  = (const float*)d_in[1];
    const float* b_hs  = (const float*)d_in[2];
    const float* w_ls  = (const float*)d_in[3];
    const float* b_ls  = (const float*)d_in[4];
    const float* w_hi1 = (const float*)d_in[5];
    const float* b_hi1 = (const float*)d_in[6];
    const float* w_hi2 = (const float*)d_in[7];
    const float* b_hi2 = (const float*)d_in[8];
    const float* w_li1 = (const float*)d_in[9];
    const float* b_li1 = (const float*)d_in[10];
    const float* w_li2 = (const float*)d_in[11];
    const float* b_li2 = (const float*)d_in[12];
    const float* w_fc1 = (const float*)d_in[13];
    const float* b_fc1 = (const float*)d_in[14];
    const float* w_fc2 = (const float*)d_in[15];
    const float* b_fc2 = (const float*)d_in[16];
    float* out = (float*)d_out;

    const int B = in_sizes[0] / (T_LEN * C_CH);    // 2048

    char* ws = (char*)d_ws;
    const size_t featB = (size_t)B * KPAD * 2;         // 29.4 MB
    const size_t wbB   = (size_t)NPAD * KPAD * 2;      // 29.4 MB
    const size_t slabB = (size_t)NPAD * NPAD * 4;      // 16.8 MB
    const size_t xtB   = (size_t)T_LEN * C_CH * B * 4; // 51.9 MB
    const size_t base2 = featB + wbB;

    __hip_bfloat16* feat = (__hip_bfloat16*)ws;
    __hip_bfloat16* wb   = (__hip_bfloat16*)(ws + featB);
    float* h1            = (float*)(ws + base2);

    const int sk = (ws_size >= base2 + 4 * slabB) ? 4 : 2;
    const bool use_xt = (ws_size >= base2 + sk * slabB + xtB);
    float* xT = (float*)(ws + base2 + sk * slabB);

    pad_w_kernel<<<dim3((NPAD * 896) / 256), 256, 0, stream>>>(w_fc1, wb);

    const float* cx = x;
    int ts = C_CH, bsi = T_LEN * C_CH, cs = 1;
    if (use_xt) {
        transpose_kernel<<<dim3(99, B / 64), 256, 0, stream>>>(x, xT, B);
        cx = xT; ts = C_CH * B; bsi = 1; cs = B;
    }
    // high (K=7) -> cols 60..107; low (K=3) -> cols 12..59 + orig/tail
    conv_kernel<7, false><<<dim3(B / 64, C_CH), 64, 0, stream>>>(
        cx, ts, bsi, cs, w_hs, b_hs, w_hi1, b_hi1, w_hi2, b_hi2, feat, 60);
    conv_kernel<3, true><<<dim3(B / 64, C_CH), 64, 0, stream>>>(
        cx, ts, bsi, cs, w_ls, b_ls, w_li1, b_li1, w_li2, b_li2, feat, 12);
    gemm_kernel<<<dim3(NPAD / 128, B / 128, sk), 256, 0, stream>>>(
        feat, wb, h1, KPAD / sk);
    fc2_kernel<<<dim3(B), 256, 0, stream>>>(h1, b_fc1, w_fc2, b_fc2, out, sk);
}